// Round 1
// baseline (997.126 us; speedup 1.0000x reference)
//
#include <hip/hip_runtime.h>
#include <hip/hip_bf16.h>
#include <math.h>

#define NN 100000
#define NE 3200000
#define NF 512

// ---------------- init: deg=1 (self loop), pooled=0 ----------------
__global__ void k_init(float* __restrict__ deg, float* __restrict__ pooled) {
    int i = blockIdx.x * blockDim.x + threadIdx.x;
    if (i < NN) deg[i] = 1.0f;
    if (i < 16) pooled[i] = 0.0f;
}

// ---------------- degree: atomicAdd over dst ----------------
__global__ void k_deg(const int* __restrict__ dst, float* __restrict__ deg) {
    int e = blockIdx.x * blockDim.x + threadIdx.x;
    if (e < NE) atomicAdd(&deg[dst[e]], 1.0f);
}

__global__ void k_dinv(const float* __restrict__ deg, float* __restrict__ dinv) {
    int i = blockIdx.x * blockDim.x + threadIdx.x;
    if (i < NN) dinv[i] = rsqrtf(deg[i]);
}

// ---------------- GEMM1: h1 = x @ W1 ; out1 = dinv^2 * h1 (self-loop init) ----
// One wave per node. Lane l covers k in {4l..4l+3, 256+4l..256+4l+3}.
// W1 slice (8 rows x 16 cols = 128 floats) lives in registers, loaded once.
__global__ __launch_bounds__(256, 2) void k_gemm1(
    const float* __restrict__ x, const float* __restrict__ W1,
    const float* __restrict__ dinv, float* __restrict__ h1,
    float* __restrict__ out1) {
    const int lane = threadIdx.x & 63;
    const int wave = blockIdx.x * (blockDim.x >> 6) + (threadIdx.x >> 6);
    const int total_waves = (gridDim.x * blockDim.x) >> 6;

    const float4* W4 = (const float4*)W1;  // W1[k][c]: float4 idx = k*4 + j
    float4 wv[2][4][4];
#pragma unroll
    for (int h = 0; h < 2; ++h)
#pragma unroll
        for (int r = 0; r < 4; ++r)
#pragma unroll
            for (int j = 0; j < 4; ++j)
                wv[h][r][j] = W4[(h * 256 + 4 * lane + r) * 4 + j];

    for (int n = wave; n < NN; n += total_waves) {
        const float4* xrow = (const float4*)(x + (size_t)n * NF);
        float4 xa = xrow[lane];       // k = 4l..4l+3
        float4 xb = xrow[64 + lane];  // k = 256+4l..
        const float* xaf = (const float*)&xa;
        const float* xbf = (const float*)&xb;

        float v[16];
#pragma unroll
        for (int c = 0; c < 16; ++c) v[c] = 0.0f;

#pragma unroll
        for (int r = 0; r < 4; ++r) {
            float va = xaf[r], vb = xbf[r];
#pragma unroll
            for (int j = 0; j < 4; ++j) {
                v[4 * j + 0] += va * wv[0][r][j].x + vb * wv[1][r][j].x;
                v[4 * j + 1] += va * wv[0][r][j].y + vb * wv[1][r][j].y;
                v[4 * j + 2] += va * wv[0][r][j].z + vb * wv[1][r][j].z;
                v[4 * j + 3] += va * wv[0][r][j].w + vb * wv[1][r][j].w;
            }
        }

        // fold reduce-scatter across 16-lane groups: lane ends with channel
        // c = bitrev4(lane&15)
#pragma unroll
        for (int s = 0; s < 4; ++s) {
            const int m = 1 << s;
            const int half = 8 >> s;
            const bool hi = (lane & m) != 0;
#pragma unroll
            for (int j = 0; j < 8; ++j) {
                if (j < half) {
                    float send = hi ? v[j] : v[j + half];
                    float recv = __shfl_xor(send, m, 64);
                    v[j] = (hi ? v[j + half] : v[j]) + recv;
                }
            }
        }
        v[0] += __shfl_xor(v[0], 16, 64);
        v[0] += __shfl_xor(v[0], 32, 64);

        if (lane < 16) {
            int c = ((lane & 1) << 3) | ((lane & 2) << 1) | ((lane & 4) >> 1) |
                    ((lane & 8) >> 3);
            float s = v[0];
            float di = dinv[n];
            h1[n * 16 + c] = s;
            out1[n * 16 + c] = di * di * s;
        }
    }
}

// ---------------- scatter: out[dst] += dinv[s]*dinv[d] * h[src] ----------------
// one thread per (edge, channel)
__global__ void k_scatter(const int* __restrict__ src, const int* __restrict__ dst,
                          const float* __restrict__ dinv, const float* __restrict__ h,
                          float* out) {
    int t = blockIdx.x * blockDim.x + threadIdx.x;
    if (t >= NE * 16) return;
    int e = t >> 4;
    int c = t & 15;
    int s = src[e];
    int d = dst[e];
    float nrm = dinv[s] * dinv[d];
    atomicAdd(&out[d * 16 + c], nrm * h[s * 16 + c]);
}

// ---------------- GEMM2: z = relu(out1+b1) @ W2 ; out2 = dinv^2 * z ------------
// one thread per node; out2 may alias out1 (reads complete before writes),
// so no __restrict__ on those.
__global__ void k_gemm2(const float* out1, const float* __restrict__ W2,
                        const float* __restrict__ b1, const float* __restrict__ dinv,
                        float* z, float* out2) {
    int n = blockIdx.x * blockDim.x + threadIdx.x;
    if (n >= NN) return;
    float hv[16];
    {
        const float4* row = (const float4*)(out1 + (size_t)n * 16);
        float4 r0 = row[0], r1 = row[1], r2 = row[2], r3 = row[3];
        ((float4*)hv)[0] = r0;
        ((float4*)hv)[1] = r1;
        ((float4*)hv)[2] = r2;
        ((float4*)hv)[3] = r3;
    }
    float acc[16];
#pragma unroll
    for (int c = 0; c < 16; ++c) acc[c] = 0.0f;
#pragma unroll
    for (int c = 0; c < 16; ++c) {
        float hc = hv[c] + b1[c];
        hc = fmaxf(hc, 0.0f);
#pragma unroll
        for (int c2 = 0; c2 < 16; ++c2) acc[c2] += hc * W2[c * 16 + c2];
    }
    float di = dinv[n];
    float d2 = di * di;
    float zz[16], oo[16];
#pragma unroll
    for (int c = 0; c < 16; ++c) {
        zz[c] = acc[c];
        oo[c] = d2 * acc[c];
    }
    float4* zr = (float4*)(z + (size_t)n * 16);
    float4* orow = (float4*)(out2 + (size_t)n * 16);
    zr[0] = ((float4*)zz)[0];
    zr[1] = ((float4*)zz)[1];
    zr[2] = ((float4*)zz)[2];
    zr[3] = ((float4*)zz)[3];
    orow[0] = ((float4*)oo)[0];
    orow[1] = ((float4*)oo)[1];
    orow[2] = ((float4*)oo)[2];
    orow[3] = ((float4*)oo)[3];
}

// ---------------- reduce: pooled[c] = sum_n out2[n][c] ----------------
__global__ void k_reduce(const float* __restrict__ out2, float* __restrict__ pooled) {
    int t = blockIdx.x * blockDim.x + threadIdx.x;
    int c = t & 15;
    int n0 = t >> 4;
    int nstride = (gridDim.x * blockDim.x) >> 4;
    float s = 0.0f;
    for (int n = n0; n < NN; n += nstride) s += out2[n * 16 + c];
    s += __shfl_xor(s, 16, 64);
    s += __shfl_xor(s, 32, 64);
    __shared__ float red[4][16];
    int wid = threadIdx.x >> 6;
    int lane = threadIdx.x & 63;
    if (lane < 16) red[wid][lane] = s;
    __syncthreads();
    if (threadIdx.x < 16) {
        float tot = red[0][threadIdx.x] + red[1][threadIdx.x] + red[2][threadIdx.x] +
                    red[3][threadIdx.x];
        atomicAdd(&pooled[threadIdx.x], tot);
    }
}

// ---------------- softmax over 16 pooled means + b2 ----------------
__global__ void k_softmax(const float* __restrict__ pooled,
                          const float* __restrict__ b2, float* __restrict__ out) {
    __shared__ float vals[16];
    int c = threadIdx.x;
    if (c < 16) vals[c] = pooled[c] * (1.0f / NN) + b2[c];
    __syncthreads();
    if (c < 16) {
        float m = -INFINITY;
        for (int i = 0; i < 16; ++i) m = fmaxf(m, vals[i]);
        float sum = 0.0f;
        for (int i = 0; i < 16; ++i) sum += expf(vals[i] - m);
        out[c] = expf(vals[c] - m) / sum;
    }
}

extern "C" void kernel_launch(void* const* d_in, const int* in_sizes, int n_in,
                              void* d_out, int out_size, void* d_ws, size_t ws_size,
                              hipStream_t stream) {
    const float* x = (const float*)d_in[0];
    const int* edge = (const int*)d_in[1];
    const float* W1 = (const float*)d_in[2];
    const float* b1 = (const float*)d_in[3];
    const float* W2 = (const float*)d_in[4];
    const float* b2 = (const float*)d_in[5];
    const int* src = edge;
    const int* dst = edge + NE;

    float* ws = (float*)d_ws;
    float* deg = ws;                    // NN
    float* dinv = ws + NN;              // NN
    float* hbuf = ws + 2 * NN;          // NN*16  (h1, then z)
    float* obuf = hbuf + NN * 16;       // NN*16  (out1, then out2)
    float* pooled = obuf + NN * 16;     // 16

    float* out = (float*)d_out;

    k_init<<<(NN + 255) / 256, 256, 0, stream>>>(deg, pooled);
    k_deg<<<(NE + 255) / 256, 256, 0, stream>>>(dst, deg);
    k_dinv<<<(NN + 255) / 256, 256, 0, stream>>>(deg, dinv);
    // 2048 blocks * 4 waves = 8192 waves, ~12 nodes each (W regs amortized)
    k_gemm1<<<2048, 256, 0, stream>>>(x, W1, dinv, hbuf, obuf);
    k_scatter<<<(NE * 16 + 255) / 256, 256, 0, stream>>>(src, dst, dinv, hbuf, obuf);
    // gemm2 reads obuf (out1) and overwrites it (out2); z goes into hbuf
    k_gemm2<<<(NN + 255) / 256, 256, 0, stream>>>(obuf, W2, b1, dinv, hbuf, obuf);
    k_scatter<<<(NE * 16 + 255) / 256, 256, 0, stream>>>(src, dst, dinv, hbuf, obuf);
    k_reduce<<<256, 256, 0, stream>>>(obuf, pooled);
    k_softmax<<<1, 64, 0, stream>>>(pooled, b2, out);
}

// Round 2
// 823.067 us; speedup vs baseline: 1.2115x; 1.2115x over previous
//
#include <hip/hip_runtime.h>
#include <hip/hip_bf16.h>
#include <math.h>

#define NN 100000
#define NE 3200000
#define NF 512
#define NTILE 6250  // NN/16 exactly

typedef __attribute__((ext_vector_type(8))) short short8;
typedef __attribute__((ext_vector_type(4))) float f32x4;

__device__ inline unsigned bf16_rne(float f) {
    unsigned u = __builtin_bit_cast(unsigned, f);
    return (u + 0x7FFFu + ((u >> 16) & 1u)) >> 16;
}
__device__ inline float bf16_back(unsigned h) {
    return __builtin_bit_cast(float, h << 16);
}

// ---------------- init: deg=1 (self loop), pooled=0 ----------------
__global__ void k_init(float* __restrict__ deg, float* __restrict__ pooled) {
    int i = blockIdx.x * blockDim.x + threadIdx.x;
    if (i < NN) deg[i] = 1.0f;
    if (i < 16) pooled[i] = 0.0f;
}

// ---------------- degree: atomicAdd over dst ----------------
__global__ void k_deg(const int* __restrict__ dst, float* __restrict__ deg) {
    int e = blockIdx.x * blockDim.x + threadIdx.x;
    if (e < NE) atomicAdd(&deg[dst[e]], 1.0f);
}

__global__ void k_dinv(const float* __restrict__ deg, float* __restrict__ dinv) {
    int i = blockIdx.x * blockDim.x + threadIdx.x;
    if (i < NN) dinv[i] = rsqrtf(deg[i]);
}

// ---------------- GEMM1 via MFMA 16x16x32 bf16, split hi/lo for fp32 accuracy --
// One wave per 16-node tile. W pre-split into bf16 (hi,lo) fragments in LDS
// once per block. x rows streamed from global directly in A-fragment layout:
// A[m=lane&15][k=q*8+j], q=lane>>4. 3 MFMAs/kk: hh + hl + lh (ll term ~2e-6).
__global__ __launch_bounds__(256) void k_gemm1(
    const float* __restrict__ x, const float* __restrict__ W1,
    const float* __restrict__ dinv, float* __restrict__ h1,
    float* __restrict__ out1) {
    __shared__ short8 Bh[1024];  // idx = (kk*4+q)*16 + c
    __shared__ short8 Bl[1024];

    const int t = threadIdx.x;
    {   // stage W: thread (c,q,kk0) handles kk = kk0*4+i
        const int c = t & 15, q = (t >> 4) & 3, kk0 = t >> 6;
        for (int i = 0; i < 4; ++i) {
            const int kk = kk0 * 4 + i;
            short8 hi, lo;
#pragma unroll
            for (int j = 0; j < 8; ++j) {
                float w = W1[(kk * 32 + q * 8 + j) * 16 + c];
                unsigned h = bf16_rne(w);
                float back = bf16_back(h);
                unsigned l = bf16_rne(w - back);
                hi[j] = (short)h;
                lo[j] = (short)l;
            }
            Bh[(kk * 4 + q) * 16 + c] = hi;
            Bl[(kk * 4 + q) * 16 + c] = lo;
        }
    }
    __syncthreads();

    const int lane = t & 63;
    const int wave = blockIdx.x * 4 + (t >> 6);
    if (wave >= NTILE) return;
    const int nb = wave * 16;
    const int m = lane & 15;  // A row within tile AND B/C col (channel)
    const int q = lane >> 4;

    // preload the whole 16-node x slice this lane needs (32 dwordx4 in flight)
    const float4* xrow = (const float4*)(x + (size_t)(nb + m) * NF + q * 8);
    float4 xr[32];
#pragma unroll
    for (int kk = 0; kk < 16; ++kk) {
        xr[2 * kk] = xrow[kk * 8];
        xr[2 * kk + 1] = xrow[kk * 8 + 1];
    }

    f32x4 acc = {0.f, 0.f, 0.f, 0.f};
#pragma unroll
    for (int kk = 0; kk < 16; ++kk) {
        float f[8] = {xr[2 * kk].x,     xr[2 * kk].y,     xr[2 * kk].z,
                      xr[2 * kk].w,     xr[2 * kk + 1].x, xr[2 * kk + 1].y,
                      xr[2 * kk + 1].z, xr[2 * kk + 1].w};
        short8 ah, al;
#pragma unroll
        for (int j = 0; j < 8; ++j) {
            unsigned h = bf16_rne(f[j]);
            ah[j] = (short)h;
            al[j] = (short)bf16_rne(f[j] - bf16_back(h));
        }
        short8 bh = Bh[(kk * 4 + q) * 16 + m];
        short8 bl = Bl[(kk * 4 + q) * 16 + m];
        acc = __builtin_amdgcn_mfma_f32_16x16x32_bf16(ah, bh, acc, 0, 0, 0);
        acc = __builtin_amdgcn_mfma_f32_16x16x32_bf16(ah, bl, acc, 0, 0, 0);
        acc = __builtin_amdgcn_mfma_f32_16x16x32_bf16(al, bh, acc, 0, 0, 0);
    }

    // C/D: col=lane&15, row=q*4+reg  [verified mapping]
#pragma unroll
    for (int r = 0; r < 4; ++r) {
        const int n = nb + q * 4 + r;
        float s = acc[r];
        float di = dinv[n];
        h1[n * 16 + m] = s;
        out1[n * 16 + m] = di * di * s;
    }
}

// ---------------- scatter: out[dst] += dinv[s]*dinv[d] * h[src] ----------------
// one thread per (edge, channel)
__global__ void k_scatter(const int* __restrict__ src, const int* __restrict__ dst,
                          const float* __restrict__ dinv, const float* __restrict__ h,
                          float* out) {
    int t = blockIdx.x * blockDim.x + threadIdx.x;
    if (t >= NE * 16) return;
    int e = t >> 4;
    int c = t & 15;
    int s = src[e];
    int d = dst[e];
    float nrm = dinv[s] * dinv[d];
    atomicAdd(&out[d * 16 + c], nrm * h[s * 16 + c]);
}

// ---------------- GEMM2: z = relu(out1+b1) @ W2 ; out2 = dinv^2 * z ------------
__global__ void k_gemm2(const float* out1, const float* __restrict__ W2,
                        const float* __restrict__ b1, const float* __restrict__ dinv,
                        float* z, float* out2) {
    int n = blockIdx.x * blockDim.x + threadIdx.x;
    if (n >= NN) return;
    float hv[16];
    {
        const float4* row = (const float4*)(out1 + (size_t)n * 16);
        float4 r0 = row[0], r1 = row[1], r2 = row[2], r3 = row[3];
        ((float4*)hv)[0] = r0;
        ((float4*)hv)[1] = r1;
        ((float4*)hv)[2] = r2;
        ((float4*)hv)[3] = r3;
    }
    float acc[16];
#pragma unroll
    for (int c = 0; c < 16; ++c) acc[c] = 0.0f;
#pragma unroll
    for (int c = 0; c < 16; ++c) {
        float hc = hv[c] + b1[c];
        hc = fmaxf(hc, 0.0f);
#pragma unroll
        for (int c2 = 0; c2 < 16; ++c2) acc[c2] += hc * W2[c * 16 + c2];
    }
    float di = dinv[n];
    float d2 = di * di;
    float zz[16], oo[16];
#pragma unroll
    for (int c = 0; c < 16; ++c) {
        zz[c] = acc[c];
        oo[c] = d2 * acc[c];
    }
    float4* zr = (float4*)(z + (size_t)n * 16);
    float4* orow = (float4*)(out2 + (size_t)n * 16);
    zr[0] = ((float4*)zz)[0];
    zr[1] = ((float4*)zz)[1];
    zr[2] = ((float4*)zz)[2];
    zr[3] = ((float4*)zz)[3];
    orow[0] = ((float4*)oo)[0];
    orow[1] = ((float4*)oo)[1];
    orow[2] = ((float4*)oo)[2];
    orow[3] = ((float4*)oo)[3];
}

// ---------------- reduce: pooled[c] = sum_n out2[n][c] ----------------
__global__ void k_reduce(const float* __restrict__ out2, float* __restrict__ pooled) {
    int t = blockIdx.x * blockDim.x + threadIdx.x;
    int c = t & 15;
    int n0 = t >> 4;
    int nstride = (gridDim.x * blockDim.x) >> 4;
    float s = 0.0f;
    for (int n = n0; n < NN; n += nstride) s += out2[n * 16 + c];
    s += __shfl_xor(s, 16, 64);
    s += __shfl_xor(s, 32, 64);
    __shared__ float red[4][16];
    int wid = threadIdx.x >> 6;
    int lane = threadIdx.x & 63;
    if (lane < 16) red[wid][lane] = s;
    __syncthreads();
    if (threadIdx.x < 16) {
        float tot = red[0][threadIdx.x] + red[1][threadIdx.x] + red[2][threadIdx.x] +
                    red[3][threadIdx.x];
        atomicAdd(&pooled[threadIdx.x], tot);
    }
}

// ---------------- softmax over 16 pooled means + b2 ----------------
__global__ void k_softmax(const float* __restrict__ pooled,
                          const float* __restrict__ b2, float* __restrict__ out) {
    __shared__ float vals[16];
    int c = threadIdx.x;
    if (c < 16) vals[c] = pooled[c] * (1.0f / NN) + b2[c];
    __syncthreads();
    if (c < 16) {
        float m = -INFINITY;
        for (int i = 0; i < 16; ++i) m = fmaxf(m, vals[i]);
        float sum = 0.0f;
        for (int i = 0; i < 16; ++i) sum += expf(vals[i] - m);
        out[c] = expf(vals[c] - m) / sum;
    }
}

extern "C" void kernel_launch(void* const* d_in, const int* in_sizes, int n_in,
                              void* d_out, int out_size, void* d_ws, size_t ws_size,
                              hipStream_t stream) {
    const float* x = (const float*)d_in[0];
    const int* edge = (const int*)d_in[1];
    const float* W1 = (const float*)d_in[2];
    const float* b1 = (const float*)d_in[3];
    const float* W2 = (const float*)d_in[4];
    const float* b2 = (const float*)d_in[5];
    const int* src = edge;
    const int* dst = edge + NE;

    float* ws = (float*)d_ws;
    float* deg = ws;                 // NN
    float* dinv = ws + NN;           // NN
    float* hbuf = ws + 2 * NN;       // NN*16  (h1, then z)
    float* obuf = hbuf + NN * 16;    // NN*16  (out1, then out2)
    float* pooled = obuf + NN * 16;  // 16

    float* out = (float*)d_out;

    k_init<<<(NN + 255) / 256, 256, 0, stream>>>(deg, pooled);
    k_deg<<<(NE + 255) / 256, 256, 0, stream>>>(dst, deg);
    k_dinv<<<(NN + 255) / 256, 256, 0, stream>>>(deg, dinv);
    k_gemm1<<<(NTILE + 3) / 4, 256, 0, stream>>>(x, W1, dinv, hbuf, obuf);
    k_scatter<<<(NE * 16 + 255) / 256, 256, 0, stream>>>(src, dst, dinv, hbuf, obuf);
    k_gemm2<<<(NN + 255) / 256, 256, 0, stream>>>(obuf, W2, b1, dinv, hbuf, obuf);
    k_scatter<<<(NE * 16 + 255) / 256, 256, 0, stream>>>(src, dst, dinv, hbuf, obuf);
    k_reduce<<<256, 256, 0, stream>>>(obuf, pooled);
    k_softmax<<<1, 64, 0, stream>>>(pooled, b2, out);
}

// Round 3
// 731.122 us; speedup vs baseline: 1.3638x; 1.1258x over previous
//
#include <hip/hip_runtime.h>
#include <hip/hip_bf16.h>
#include <math.h>

#define NN 100000
#define NE 3200000
#define NF 512
#define NTILE 6250   // NN/16 exactly
#define SCAN_B 512
#define NSB ((NN + SCAN_B - 1) / SCAN_B)  // 196

typedef __attribute__((ext_vector_type(8))) short short8;
typedef __attribute__((ext_vector_type(4))) float f32x4;

__device__ inline unsigned bf16_rne(float f) {
    unsigned u = __builtin_bit_cast(unsigned, f);
    return (u + 0x7FFFu + ((u >> 16) & 1u)) >> 16;
}
__device__ inline float bf16_back(unsigned h) {
    return __builtin_bit_cast(float, h << 16);
}

// ---------------- init: cnt=0, cursor=0, pooled=0 ----------------
__global__ void k_init(int* __restrict__ cnt, int* __restrict__ cursor,
                       float* __restrict__ pooled) {
    int i = blockIdx.x * blockDim.x + threadIdx.x;
    if (i < NN) {
        cnt[i] = 0;
        cursor[i] = 0;
    }
    if (i < 16) pooled[i] = 0.0f;
}

// ---------------- in-degree histogram (excl self-loop) ----------------
__global__ void k_count(const int* __restrict__ dst, int* __restrict__ cnt) {
    int e = blockIdx.x * blockDim.x + threadIdx.x;
    if (e < NE) atomicAdd(&cnt[dst[e]], 1);
}

__global__ void k_dinv(const int* __restrict__ cnt, float* __restrict__ dinv) {
    int i = blockIdx.x * blockDim.x + threadIdx.x;
    if (i < NN) dinv[i] = rsqrtf((float)cnt[i] + 1.0f);  // +1 self-loop
}

// ---------------- 3-kernel exclusive scan of cnt -> row_start ----------------
__global__ void k_scan1(const int* __restrict__ cnt, int* __restrict__ row_start,
                        int* __restrict__ bsum) {
    __shared__ int tmp[2][SCAN_B];
    int tid = threadIdx.x;
    int i = blockIdx.x * SCAN_B + tid;
    int v = (i < NN) ? cnt[i] : 0;
    int pp = 0;
    tmp[0][tid] = v;
    __syncthreads();
    for (int off = 1; off < SCAN_B; off <<= 1) {
        int t = tmp[pp][tid];
        if (tid >= off) t += tmp[pp][tid - off];
        tmp[1 - pp][tid] = t;
        __syncthreads();
        pp = 1 - pp;
    }
    int incl = tmp[pp][tid];
    if (i < NN) row_start[i] = incl - v;  // exclusive, sans block offset
    if (tid == SCAN_B - 1) bsum[blockIdx.x] = incl;
}

__global__ void k_scan2(int* __restrict__ bsum) {
    __shared__ int tmp[2][256];
    int tid = threadIdx.x;
    int v = (tid < NSB) ? bsum[tid] : 0;
    int pp = 0;
    tmp[0][tid] = v;
    __syncthreads();
    for (int off = 1; off < 256; off <<= 1) {
        int t = tmp[pp][tid];
        if (tid >= off) t += tmp[pp][tid - off];
        tmp[1 - pp][tid] = t;
        __syncthreads();
        pp = 1 - pp;
    }
    if (tid < NSB) bsum[tid] = tmp[pp][tid] - v;  // exclusive
}

__global__ void k_scan3(int* __restrict__ row_start, const int* __restrict__ bsum) {
    int i = blockIdx.x * blockDim.x + threadIdx.x;
    if (i < NN) row_start[i] += bsum[i >> 9];
    if (i == 0) row_start[NN] = NE;
}

// ---------------- CSR fill: csr[row_start[d] + pos] = src ----------------
__global__ void k_fill(const int* __restrict__ src, const int* __restrict__ dst,
                       const int* __restrict__ row_start, int* __restrict__ cursor,
                       int* __restrict__ csr) {
    int e = blockIdx.x * blockDim.x + threadIdx.x;
    if (e >= NE) return;
    int d = dst[e];
    int pos = atomicAdd(&cursor[d], 1);
    csr[row_start[d] + pos] = src[e];
}

// ---------------- GEMM1 via MFMA 16x16x32 bf16, split hi/lo ----------------
// Writes h_scaled[n][c] = dinv[n] * (x@W1)[n][c]
__global__ __launch_bounds__(256) void k_gemm1(
    const float* __restrict__ x, const float* __restrict__ W1,
    const float* __restrict__ dinv, float* __restrict__ hs) {
    __shared__ short8 Bh[1024];  // idx = (kk*4+q)*16 + c
    __shared__ short8 Bl[1024];

    const int t = threadIdx.x;
    {   // stage W: thread (c,q,kk0) handles kk = kk0*4+i
        const int c = t & 15, q = (t >> 4) & 3, kk0 = t >> 6;
        for (int i = 0; i < 4; ++i) {
            const int kk = kk0 * 4 + i;
            short8 hi, lo;
#pragma unroll
            for (int j = 0; j < 8; ++j) {
                float w = W1[(kk * 32 + q * 8 + j) * 16 + c];
                unsigned h = bf16_rne(w);
                float back = bf16_back(h);
                unsigned l = bf16_rne(w - back);
                hi[j] = (short)h;
                lo[j] = (short)l;
            }
            Bh[(kk * 4 + q) * 16 + c] = hi;
            Bl[(kk * 4 + q) * 16 + c] = lo;
        }
    }
    __syncthreads();

    const int lane = t & 63;
    const int wave = blockIdx.x * 4 + (t >> 6);
    if (wave >= NTILE) return;
    const int nb = wave * 16;
    const int m = lane & 15;  // A row within tile AND B/C col (channel)
    const int q = lane >> 4;

    const float4* xrow = (const float4*)(x + (size_t)(nb + m) * NF + q * 8);
    float4 xr[32];
#pragma unroll
    for (int kk = 0; kk < 16; ++kk) {
        xr[2 * kk] = xrow[kk * 8];
        xr[2 * kk + 1] = xrow[kk * 8 + 1];
    }

    f32x4 acc = {0.f, 0.f, 0.f, 0.f};
#pragma unroll
    for (int kk = 0; kk < 16; ++kk) {
        float f[8] = {xr[2 * kk].x,     xr[2 * kk].y,     xr[2 * kk].z,
                      xr[2 * kk].w,     xr[2 * kk + 1].x, xr[2 * kk + 1].y,
                      xr[2 * kk + 1].z, xr[2 * kk + 1].w};
        short8 ah, al;
#pragma unroll
        for (int j = 0; j < 8; ++j) {
            unsigned h = bf16_rne(f[j]);
            ah[j] = (short)h;
            al[j] = (short)bf16_rne(f[j] - bf16_back(h));
        }
        short8 bh = Bh[(kk * 4 + q) * 16 + m];
        short8 bl = Bl[(kk * 4 + q) * 16 + m];
        acc = __builtin_amdgcn_mfma_f32_16x16x32_bf16(ah, bh, acc, 0, 0, 0);
        acc = __builtin_amdgcn_mfma_f32_16x16x32_bf16(ah, bl, acc, 0, 0, 0);
        acc = __builtin_amdgcn_mfma_f32_16x16x32_bf16(al, bh, acc, 0, 0, 0);
    }

    // C/D: col=lane&15, row=q*4+reg
#pragma unroll
    for (int r = 0; r < 4; ++r) {
        const int n = nb + q * 4 + r;
        hs[n * 16 + m] = dinv[n] * acc[r];
    }
}

// ---------------- gather: out[n] = dinv[n]*(hs[n] + sum_{s in N(n)} hs[s]) ------
// one wave per node; lanes = (edge subgroup g=lane>>4) x (channel c=lane&15)
__global__ __launch_bounds__(256) void k_gather(
    const float* __restrict__ hs, const float* __restrict__ dinv,
    const int* __restrict__ row_start, const int* __restrict__ csr,
    float* __restrict__ out) {
    const int lane = threadIdx.x & 63;
    const int n = blockIdx.x * 4 + (threadIdx.x >> 6);
    const int c = lane & 15;
    const int g = lane >> 4;
    const int beg = row_start[n], end = row_start[n + 1];
    float acc = 0.0f;
    int i = beg + g;
    for (; i + 4 < end; i += 8) {  // 2 edges per group per iter (MLP)
        int s0 = csr[i];
        int s1 = csr[i + 4];
        acc += hs[s0 * 16 + c];
        acc += hs[s1 * 16 + c];
    }
    if (i < end) {
        int s0 = csr[i];
        acc += hs[s0 * 16 + c];
    }
    acc += __shfl_xor(acc, 16, 64);
    acc += __shfl_xor(acc, 32, 64);
    if (lane < 16) out[n * 16 + c] = dinv[n] * (acc + hs[n * 16 + c]);
}

// ---------------- GEMM2: hs2[n] = dinv[n] * (relu(a1+b1) @ W2) ----------------
__global__ void k_gemm2(const float* __restrict__ a1, const float* __restrict__ W2,
                        const float* __restrict__ b1, const float* __restrict__ dinv,
                        float* __restrict__ hs2) {
    int n = blockIdx.x * blockDim.x + threadIdx.x;
    if (n >= NN) return;
    float hv[16];
    {
        const float4* row = (const float4*)(a1 + (size_t)n * 16);
        ((float4*)hv)[0] = row[0];
        ((float4*)hv)[1] = row[1];
        ((float4*)hv)[2] = row[2];
        ((float4*)hv)[3] = row[3];
    }
    float acc[16];
#pragma unroll
    for (int c = 0; c < 16; ++c) acc[c] = 0.0f;
#pragma unroll
    for (int c = 0; c < 16; ++c) {
        float hc = fmaxf(hv[c] + b1[c], 0.0f);
#pragma unroll
        for (int c2 = 0; c2 < 16; ++c2) acc[c2] += hc * W2[c * 16 + c2];
    }
    float di = dinv[n];
    float oo[16];
#pragma unroll
    for (int c = 0; c < 16; ++c) oo[c] = di * acc[c];
    float4* orow = (float4*)(hs2 + (size_t)n * 16);
    orow[0] = ((float4*)oo)[0];
    orow[1] = ((float4*)oo)[1];
    orow[2] = ((float4*)oo)[2];
    orow[3] = ((float4*)oo)[3];
}

// ---------------- reduce: pooled[c] = sum_n out2[n][c] ----------------
__global__ void k_reduce(const float* __restrict__ out2, float* __restrict__ pooled) {
    int t = blockIdx.x * blockDim.x + threadIdx.x;
    int c = t & 15;
    int n0 = t >> 4;
    int nstride = (gridDim.x * blockDim.x) >> 4;
    float s = 0.0f;
    for (int n = n0; n < NN; n += nstride) s += out2[n * 16 + c];
    s += __shfl_xor(s, 16, 64);
    s += __shfl_xor(s, 32, 64);
    __shared__ float red[4][16];
    int wid = threadIdx.x >> 6;
    int lane = threadIdx.x & 63;
    if (lane < 16) red[wid][lane] = s;
    __syncthreads();
    if (threadIdx.x < 16) {
        float tot = red[0][threadIdx.x] + red[1][threadIdx.x] + red[2][threadIdx.x] +
                    red[3][threadIdx.x];
        atomicAdd(&pooled[threadIdx.x], tot);
    }
}

// ---------------- softmax over 16 pooled means + b2 ----------------
__global__ void k_softmax(const float* __restrict__ pooled,
                          const float* __restrict__ b2, float* __restrict__ out) {
    __shared__ float vals[16];
    int c = threadIdx.x;
    if (c < 16) vals[c] = pooled[c] * (1.0f / NN) + b2[c];
    __syncthreads();
    if (c < 16) {
        float m = -INFINITY;
        for (int i = 0; i < 16; ++i) m = fmaxf(m, vals[i]);
        float sum = 0.0f;
        for (int i = 0; i < 16; ++i) sum += expf(vals[i] - m);
        out[c] = expf(vals[c] - m) / sum;
    }
}

extern "C" void kernel_launch(void* const* d_in, const int* in_sizes, int n_in,
                              void* d_out, int out_size, void* d_ws, size_t ws_size,
                              hipStream_t stream) {
    const float* x = (const float*)d_in[0];
    const int* edge = (const int*)d_in[1];
    const float* W1 = (const float*)d_in[2];
    const float* b1 = (const float*)d_in[3];
    const float* W2 = (const float*)d_in[4];
    const float* b2 = (const float*)d_in[5];
    const int* src = edge;
    const int* dst = edge + NE;

    char* ws = (char*)d_ws;
    int* cnt = (int*)ws;                      // NN
    int* row_start = cnt + NN;                // NN+1
    int* cursor = row_start + NN + 1;         // NN
    int* bsum = cursor + NN;                  // 256
    int* csr = bsum + 256;                    // NE
    float* dinv = (float*)(csr + NE);         // NN
    float* hbuf = dinv + NN;                  // NN*16 (h_scaled)
    float* abuf = hbuf + (size_t)NN * 16;     // NN*16 (aggregated)
    float* pooled = abuf + (size_t)NN * 16;   // 16

    float* out = (float*)d_out;

    k_init<<<(NN + 255) / 256, 256, 0, stream>>>(cnt, cursor, pooled);
    k_count<<<(NE + 255) / 256, 256, 0, stream>>>(dst, cnt);
    k_dinv<<<(NN + 255) / 256, 256, 0, stream>>>(cnt, dinv);
    k_scan1<<<NSB, SCAN_B, 0, stream>>>(cnt, row_start, bsum);
    k_scan2<<<1, 256, 0, stream>>>(bsum);
    k_scan3<<<(NN + 255) / 256, 256, 0, stream>>>(row_start, bsum);
    k_fill<<<(NE + 255) / 256, 256, 0, stream>>>(src, dst, row_start, cursor, csr);

    k_gemm1<<<(NTILE + 3) / 4, 256, 0, stream>>>(x, W1, dinv, hbuf);
    k_gather<<<NN / 4, 256, 0, stream>>>(hbuf, dinv, row_start, csr, abuf);
    k_gemm2<<<(NN + 255) / 256, 256, 0, stream>>>(abuf, W2, b1, dinv, hbuf);
    k_gather<<<NN / 4, 256, 0, stream>>>(hbuf, dinv, row_start, csr, abuf);
    k_reduce<<<256, 256, 0, stream>>>(abuf, pooled);
    k_softmax<<<1, 64, 0, stream>>>(pooled, b2, out);
}